// Round 10
// baseline (359.849 us; speedup 1.0000x reference)
//
#include <hip/hip_runtime.h>
#include <hip/hip_bf16.h>

#define THR 0.1f
#define COS_EPS 1e-8f
#define LN_EPS 1e-5f

typedef short bfx8 __attribute__((ext_vector_type(8)));
typedef float fx4 __attribute__((ext_vector_type(4)));

__device__ __forceinline__ float wave_sum(float v) {
    #pragma unroll
    for (int o = 1; o < 64; o <<= 1) v += __shfl_xor(v, o);
    return v;
}
__device__ __forceinline__ float gsum16(float v) {
    #pragma unroll
    for (int o = 1; o < 16; o <<= 1) v += __shfl_xor(v, o);
    return v;
}
__device__ __forceinline__ float gmax16(float v) {
    #pragma unroll
    for (int o = 1; o < 16; o <<= 1) v = fmaxf(v, __shfl_xor(v, o));
    return v;
}

__device__ __forceinline__ unsigned short f2bf(float f) {
    unsigned int u = __float_as_uint(f);
    unsigned int r = (u + 0x7FFFu + ((u >> 16) & 1u)) >> 16;
    return (unsigned short)r;
}
__device__ __forceinline__ float bf2f(unsigned short h) {
    return __uint_as_float(((unsigned int)h) << 16);
}

// ---------------- W prep body (value-pinned: no muls -> no contraction risk) ----
template <int CF>
__device__ __forceinline__ void wprep_body(const float* __restrict__ W,
                                           unsigned short* __restrict__ P, int t) {
    const int PLANE = CF * 2048;
    if (t >= 4 * CF * 64) return;
    int lane = t & 63, fr = t >> 6;
    int cf = fr % CF, ks = fr / CF;
    int col = cf * 16 + (lane & 15);
    int k0 = ks * 32 + (lane >> 4) * 8;
    size_t base = (size_t)fr * 512 + (size_t)lane * 8;
    #pragma unroll
    for (int j = 0; j < 8; ++j) {
        float x = W[(size_t)(k0 + j) * (CF * 16) + col];
        unsigned short h = f2bf(x);
        float fh = bf2f(h);
        float r1 = x - fh;
        unsigned short m = f2bf(r1);
        float fm = bf2f(m);
        unsigned short lo = f2bf(r1 - fm);
        P[base + j] = h;
        P[PLANE + base + j] = m;
        P[2 * PLANE + base + j] = lo;
    }
}

// ---------------- fused: edge-degree count + all W plane prep ----------------
__global__ __launch_bounds__(256) void aux_k(const int* __restrict__ dst, int E,
    int* __restrict__ counts, const float* __restrict__ W0, const float* __restrict__ W1,
    const float* __restrict__ W2, unsigned short* __restrict__ P0,
    unsigned short* __restrict__ P1, unsigned short* __restrict__ P2, int gridE) {
    int bx = blockIdx.x;
    if (bx < gridE) {
        int e = bx * 256 + threadIdx.x;
        if (e < E) atomicAdd(&counts[dst[e]], 1);
    } else {
        int r = bx - gridE;
        if (r < 8) wprep_body<8>(W0, P0, r * 256 + threadIdx.x);
        else if (r < 16) wprep_body<8>(W1, P1, (r - 8) * 256 + threadIdx.x);
        else wprep_body<4>(W2, P2, (r - 16) * 256 + threadIdx.x);
    }
}

// fused scan phase 1+2: per-1024-chunk sums; last block scans the <=64 partials
__global__ void scan12_k(const int* __restrict__ counts, int* __restrict__ partials,
                         int* __restrict__ done, int ntot, int nb) {
    int base = blockIdx.x * 1024;
    int t = threadIdx.x;
    int s = 0;
    #pragma unroll
    for (int i = 0; i < 4; ++i) {
        int idx = base + t + i * 256;
        if (idx < ntot) s += counts[idx];
    }
    s = (int)wave_sum((float)s);  // exact: partial sums << 2^24
    __shared__ int ws[4];
    __shared__ int amLast;
    if ((t & 63) == 0) ws[t >> 6] = s;
    __syncthreads();
    if (t == 0) {
        partials[blockIdx.x] = ws[0] + ws[1] + ws[2] + ws[3];
        __threadfence();
        amLast = (atomicAdd(done, 1) == (int)gridDim.x - 1);
    }
    __syncthreads();
    if (amLast && t < 64) {
        __threadfence();
        int v = (t < nb) ? partials[t] : 0;
        int orig = v;
        #pragma unroll
        for (int o = 1; o < 64; o <<= 1) {
            int u = __shfl_up(v, o);
            if (t >= o) v += u;
        }
        if (t < nb) partials[t] = v - orig;
    }
}

__global__ void scan3_k(int* __restrict__ counts, const int* __restrict__ partials,
                        int* __restrict__ offs, int ntot) {
    int base = blockIdx.x * 1024;
    int t = threadIdx.x;
    int lane = t & 63, wid = t >> 6;
    int idx = base + t * 4;
    int c[4];
    #pragma unroll
    for (int k = 0; k < 4; ++k) c[k] = (idx + k < ntot) ? counts[idx + k] : 0;
    int s = c[0] + c[1] + c[2] + c[3];
    int sc = s;
    #pragma unroll
    for (int o = 1; o < 64; o <<= 1) {
        int u = __shfl_up(sc, o);
        if (lane >= o) sc += u;
    }
    __shared__ int wsum[4];
    if (lane == 63) wsum[wid] = sc;
    __syncthreads();
    int add = partials[blockIdx.x];
    for (int w = 0; w < wid; ++w) add += wsum[w];
    int ex = add + sc - s;
    #pragma unroll
    for (int k = 0; k < 4; ++k) {
        if (idx + k < ntot) {
            offs[idx + k] = ex;
            counts[idx + k] = ex;
            ex += c[k];
        }
    }
}

__global__ void scatter_k(const int* __restrict__ src, const int* __restrict__ dst, int E,
                          int* __restrict__ cursor, int* __restrict__ csr_src) {
    int e = blockIdx.x * 256 + threadIdx.x;
    if (e < E) {
        int p = atomicAdd(&cursor[dst[e]], 1);
        csr_src[p] = src[e];
    }
}

// ---------------- normalize x -> hn + norms (FROZEN: byte-exact R5) ----------------
__global__ void normpack_k(const float* __restrict__ h, float* __restrict__ hn,
                           float* __restrict__ norms, int n) {
    int node = (blockIdx.x * blockDim.x + threadIdx.x) >> 6;
    int lane = threadIdx.x & 63;
    if (node >= n) return;
    float2 v = *(const float2*)(h + (size_t)node * 128 + lane * 2);
    float ss = wave_sum(v.x * v.x + v.y * v.y);
    float nrm = sqrtf(ss);
    float inv = 1.0f / fmaxf(nrm, COS_EPS);
    float2 o = {v.x * inv, v.y * inv};
    *(float2*)(hn + (size_t)node * 128 + lane * 2) = o;
    if (lane == 0) norms[node] = nrm;
}

// ---------------- aggregation: depth-4 prefetch ring, all indices clamped --------
// Value stream identical to R5/R8: per group, edges consumed in ascending j;
// dot/threshold/accumulate expressions byte-identical; same final reduce order.
__global__ void agg_k(const float* __restrict__ hn, const float* __restrict__ norms,
                      const int* __restrict__ offs, const int* __restrict__ csr,
                      float* __restrict__ r, int n) {
    int node = (blockIdx.x * blockDim.x + threadIdx.x) >> 6;
    int lane = threadIdx.x & 63;
    if (node >= n) return;
    int g = lane >> 4;
    int q = lane & 15;
    const float* myrow = hn + (size_t)node * 128 + q * 8;
    float4 d0 = *(const float4*)myrow;
    float4 d1 = *(const float4*)(myrow + 4);
    float nd = norms[node];
    float p = d0.x * d0.x + d0.y * d0.y + d0.z * d0.z + d0.w * d0.w
            + d1.x * d1.x + d1.y * d1.y + d1.z * d1.z + d1.w * d1.w;
    p = gsum16(p);
    float4 a0 = {0.f, 0.f, 0.f, 0.f}, a1 = {0.f, 0.f, 0.f, 0.f};
    float denom = 0.f;
    int b = offs[node], e = offs[node + 1];
    for (int i0 = b; i0 < e; i0 += 64) {
        int cnt = e - i0;
        if (cnt > 64) cnt = 64;
        int sidx = csr[i0 + (lane < cnt ? lane : 0)];
        float4 pa0, pa1, pa2, pa3, pb0, pb1, pb2, pb3;
        float pv0, pv1, pv2, pv3;
        {
            int jj = g;
            jj = (jj < cnt) ? jj : 0;
            int s = __shfl(sidx, jj);
            const float* sp = hn + (size_t)s * 128 + q * 8;
            pa0 = *(const float4*)sp; pb0 = *(const float4*)(sp + 4); pv0 = norms[s];
        }
        {
            int jj = g + 4;
            jj = (jj < cnt) ? jj : 0;
            int s = __shfl(sidx, jj);
            const float* sp = hn + (size_t)s * 128 + q * 8;
            pa1 = *(const float4*)sp; pb1 = *(const float4*)(sp + 4); pv1 = norms[s];
        }
        {
            int jj = g + 8;
            jj = (jj < cnt) ? jj : 0;
            int s = __shfl(sidx, jj);
            const float* sp = hn + (size_t)s * 128 + q * 8;
            pa2 = *(const float4*)sp; pb2 = *(const float4*)(sp + 4); pv2 = norms[s];
        }
        {
            int jj = g + 12;
            jj = (jj < cnt) ? jj : 0;
            int s = __shfl(sidx, jj);
            const float* sp = hn + (size_t)s * 128 + q * 8;
            pa3 = *(const float4*)sp; pb3 = *(const float4*)(sp + 4); pv3 = norms[s];
        }
        for (int j0 = 0; j0 < cnt; j0 += 16) {
            #pragma unroll
            for (int u = 0; u < 4; ++u) {
                int j = j0 + u * 4;
                float4 c0, c1;
                float cn;
                if (u == 0) { c0 = pa0; c1 = pb0; cn = pv0; }
                else if (u == 1) { c0 = pa1; c1 = pb1; cn = pv1; }
                else if (u == 2) { c0 = pa2; c1 = pb2; cn = pv2; }
                else { c0 = pa3; c1 = pb3; cn = pv3; }
                int jn = j + 16 + g;
                jn = (jn < cnt) ? jn : 0;
                int s2 = __shfl(sidx, jn);
                const float* sp2 = hn + (size_t)s2 * 128 + q * 8;
                if (u == 0) { pa0 = *(const float4*)sp2; pb0 = *(const float4*)(sp2 + 4); pv0 = norms[s2]; }
                else if (u == 1) { pa1 = *(const float4*)sp2; pb1 = *(const float4*)(sp2 + 4); pv1 = norms[s2]; }
                else if (u == 2) { pa2 = *(const float4*)sp2; pb2 = *(const float4*)(sp2 + 4); pv2 = norms[s2]; }
                else { pa3 = *(const float4*)sp2; pb3 = *(const float4*)(sp2 + 4); pv3 = norms[s2]; }
                float t = d0.x * c0.x + d0.y * c0.y + d0.z * c0.z + d0.w * c0.w
                        + d1.x * c1.x + d1.y * c1.y + d1.z * c1.z + d1.w * c1.w;
                t = gsum16(t);
                if (j + g < cnt) {
                    float av = (t < THR) ? 1e-6f : t;
                    denom += av;
                    float w = av * cn;
                    a0.x += w * c0.x; a0.y += w * c0.y; a0.z += w * c0.z; a0.w += w * c0.w;
                    a1.x += w * c1.x; a1.y += w * c1.y; a1.z += w * c1.z; a1.w += w * c1.w;
                }
            }
        }
    }
    #pragma unroll
    for (int o = 16; o < 64; o <<= 1) {
        a0.x += __shfl_xor(a0.x, o); a0.y += __shfl_xor(a0.y, o);
        a0.z += __shfl_xor(a0.z, o); a0.w += __shfl_xor(a0.w, o);
        a1.x += __shfl_xor(a1.x, o); a1.y += __shfl_xor(a1.y, o);
        a1.z += __shfl_xor(a1.z, o); a1.w += __shfl_xor(a1.w, o);
        denom += __shfl_xor(denom, o);
    }
    // self loop
    float a = (p < THR) ? 1e-6f : p;
    denom += a;
    float w = a * nd;
    a0.x += w * d0.x; a0.y += w * d0.y; a0.z += w * d0.z; a0.w += w * d0.w;
    a1.x += w * d1.x; a1.y += w * d1.y; a1.z += w * d1.z; a1.w += w * d1.w;
    if (g == 0) {
        float inv = 1.0f / denom;
        float4 o0 = {a0.x * inv, a0.y * inv, a0.z * inv, a0.w * inv};
        float4 o1 = {a1.x * inv, a1.y * inv, a1.z * inv, a1.w * inv};
        *(float4*)(r + (size_t)node * 128 + q * 8) = o0;
        *(float4*)(r + (size_t)node * 128 + q * 8 + 4) = o1;
    }
}

// ---------------- MFMA core (FROZEN: byte-exact R5) ----------------
template <int CF>
__device__ __forceinline__ void mfma_core(const float* __restrict__ arow,
                                          const unsigned short* __restrict__ P,
                                          int lane, fx4* acc) {
    const int PLANE = CF * 2048;
    float ast[32];
    #pragma unroll
    for (int ks = 0; ks < 4; ++ks) {
        float4 u0 = *(const float4*)(arow + ks * 32);
        float4 u1 = *(const float4*)(arow + ks * 32 + 4);
        ast[ks * 8 + 0] = u0.x; ast[ks * 8 + 1] = u0.y;
        ast[ks * 8 + 2] = u0.z; ast[ks * 8 + 3] = u0.w;
        ast[ks * 8 + 4] = u1.x; ast[ks * 8 + 5] = u1.y;
        ast[ks * 8 + 6] = u1.z; ast[ks * 8 + 7] = u1.w;
    }
    #pragma unroll
    for (int ks = 0; ks < 4; ++ks) {
        bfx8 ah, am, al;
        #pragma unroll
        for (int j = 0; j < 8; ++j) {
            float x = ast[ks * 8 + j];
            unsigned short h = f2bf(x);
            float fh = bf2f(h);
            float r1 = x - fh;
            unsigned short m = f2bf(r1);
            float fm = bf2f(m);
            unsigned short lo = f2bf(r1 - fm);
            ah[j] = (short)h; am[j] = (short)m; al[j] = (short)lo;
        }
        #pragma unroll
        for (int cb = 0; cb < CF; cb += 4) {
            bfx8 bh[4], bm[4], bl[4];
            #pragma unroll
            for (int q = 0; q < 4; ++q) {
                size_t base = ((size_t)(ks * CF + cb + q) * 64 + lane) * 8;
                bh[q] = *(const bfx8*)(P + base);
                bm[q] = *(const bfx8*)(P + PLANE + base);
                bl[q] = *(const bfx8*)(P + 2 * PLANE + base);
            }
            #pragma unroll
            for (int q = 0; q < 4; ++q)
                acc[cb + q] = __builtin_amdgcn_mfma_f32_16x16x32_bf16(ah, bh[q], acc[cb + q], 0, 0, 0);
            #pragma unroll
            for (int q = 0; q < 4; ++q)
                acc[cb + q] = __builtin_amdgcn_mfma_f32_16x16x32_bf16(ah, bm[q], acc[cb + q], 0, 0, 0);
            #pragma unroll
            for (int q = 0; q < 4; ++q)
                acc[cb + q] = __builtin_amdgcn_mfma_f32_16x16x32_bf16(am, bh[q], acc[cb + q], 0, 0, 0);
            #pragma unroll
            for (int q = 0; q < 4; ++q)
                acc[cb + q] = __builtin_amdgcn_mfma_f32_16x16x32_bf16(ah, bl[q], acc[cb + q], 0, 0, 0);
            #pragma unroll
            for (int q = 0; q < 4; ++q)
                acc[cb + q] = __builtin_amdgcn_mfma_f32_16x16x32_bf16(am, bm[q], acc[cb + q], 0, 0, 0);
            #pragma unroll
            for (int q = 0; q < 4; ++q)
                acc[cb + q] = __builtin_amdgcn_mfma_f32_16x16x32_bf16(al, bh[q], acc[cb + q], 0, 0, 0);
        }
    }
}

// ---------------- MFMA GEMM + bias + LN + ReLU + renormalize (FROZEN: R5) ----------------
__global__ __launch_bounds__(256) void mgemm_ln_k(const float* __restrict__ A,
    const unsigned short* __restrict__ P, const float* __restrict__ bias,
    const float* __restrict__ g, const float* __restrict__ be,
    float* __restrict__ hn, float* __restrict__ norms, int nw, int M) {
    const int CF = 8;
    int wid = blockIdx.x * 4 + (threadIdx.x >> 6);
    if (wid >= nw) return;
    int lane = threadIdx.x & 63;
    int rsel = lane & 15, kg = lane >> 4;
    int arowi = wid * 16 + rsel;
    if (arowi >= M) arowi = M - 1;
    const float* arow = A + (size_t)arowi * 128 + kg * 8;
    fx4 acc[CF];
    #pragma unroll
    for (int c = 0; c < CF; ++c) acc[c] = (fx4){0.f, 0.f, 0.f, 0.f};
    mfma_core<CF>(arow, P, lane, acc);
    float bi[CF], gm[CF], bb[CF];
    #pragma unroll
    for (int c = 0; c < CF; ++c) {
        int col = c * 16 + rsel;
        bi[c] = bias[col]; gm[c] = g[col]; bb[c] = be[col];
    }
    #pragma unroll
    for (int r = 0; r < 4; ++r) {
        int row = wid * 16 + kg * 4 + r;
        float o[CF], s = 0.f;
        #pragma unroll
        for (int c = 0; c < CF; ++c) { o[c] = acc[c][r] + bi[c]; s += o[c]; }
        float mean = gsum16(s) * (1.f / 128.f);
        float vv = 0.f;
        #pragma unroll
        for (int c = 0; c < CF; ++c) { o[c] -= mean; vv += o[c] * o[c]; }
        float var = gsum16(vv) * (1.f / 128.f);
        float rs = rsqrtf(var + LN_EPS);
        float ss = 0.f;
        #pragma unroll
        for (int c = 0; c < CF; ++c) {
            o[c] = fmaxf(o[c] * rs * gm[c] + bb[c], 0.f);
            ss += o[c] * o[c];
        }
        float nrm = sqrtf(gsum16(ss));
        float inv = 1.f / fmaxf(nrm, COS_EPS);
        if (row < M) {
            #pragma unroll
            for (int c = 0; c < CF; ++c) hn[(size_t)row * 128 + c * 16 + rsel] = o[c] * inv;
            if (rsel == 0) norms[row] = nrm;
        }
    }
}

// ---------------- MFMA GEMM + bias + log_softmax (FROZEN: R5) ----------------
__global__ __launch_bounds__(256) void mgemm_lsm_k(const float* __restrict__ A,
    const unsigned short* __restrict__ P, const float* __restrict__ bias,
    float* __restrict__ out, int nw, int M) {
    const int CF = 4;
    int wid = blockIdx.x * 4 + (threadIdx.x >> 6);
    if (wid >= nw) return;
    int lane = threadIdx.x & 63;
    int rsel = lane & 15, kg = lane >> 4;
    int arowi = wid * 16 + rsel;
    if (arowi >= M) arowi = M - 1;
    const float* arow = A + (size_t)arowi * 128 + kg * 8;
    fx4 acc[CF];
    #pragma unroll
    for (int c = 0; c < CF; ++c) acc[c] = (fx4){0.f, 0.f, 0.f, 0.f};
    mfma_core<CF>(arow, P, lane, acc);
    float bi[CF];
    #pragma unroll
    for (int c = 0; c < CF; ++c) bi[c] = bias[c * 16 + rsel];
    #pragma unroll
    for (int r = 0; r < 4; ++r) {
        int row = wid * 16 + kg * 4 + r;
        float v[CF], mx = -1e30f;
        #pragma unroll
        for (int c = 0; c < CF; ++c) { v[c] = acc[c][r] + bi[c]; mx = fmaxf(mx, v[c]); }
        float m = gmax16(mx);
        float es = 0.f;
        #pragma unroll
        for (int c = 0; c < CF; ++c) es += __expf(v[c] - m);
        float s = gsum16(es);
        float ls = logf(s);
        if (row < M) {
            #pragma unroll
            for (int c = 0; c < CF; ++c) out[(size_t)row * 64 + c * 16 + rsel] = v[c] - m - ls;
        }
    }
}

extern "C" void kernel_launch(void* const* d_in, const int* in_sizes, int n_in,
                              void* d_out, int out_size, void* d_ws, size_t ws_size,
                              hipStream_t stream) {
    const float* x  = (const float*)d_in[0];
    const int* ei   = (const int*)d_in[1];
    const float* W0 = (const float*)d_in[2];
    const float* b0 = (const float*)d_in[3];
    const float* W1 = (const float*)d_in[4];
    const float* b1 = (const float*)d_in[5];
    const float* W2 = (const float*)d_in[6];
    const float* b2 = (const float*)d_in[7];
    const float* g1 = (const float*)d_in[8];
    const float* be1 = (const float*)d_in[9];
    const float* g2 = (const float*)d_in[10];
    const float* be2 = (const float*)d_in[11];

    const int N = in_sizes[0] / 128;
    const int E = in_sizes[1] / 2;
    const int* src = ei;
    const int* dst = ei + E;
    const int ntot = N + 1;
    const int nscan = (ntot + 1023) / 1024;

    size_t off = 0;
    auto carve = [&](size_t bytes) {
        void* p = (char*)d_ws + off;
        off += (bytes + 255) & ~(size_t)255;
        return p;
    };
    float* bufA   = (float*)carve((size_t)N * 128 * 4);
    float* bufB   = (float*)carve((size_t)N * 128 * 4);
    float* nA     = (float*)carve((size_t)N * 4);
    float* nB     = (float*)carve((size_t)N * 4);
    int* counts   = (int*)carve((size_t)(ntot + 64) * 4);  // +done counter
    int* done     = counts + ntot;
    int* offs     = (int*)carve((size_t)ntot * 4);
    int* partials = (int*)carve((size_t)256 * 4);
    int* csr      = (int*)carve((size_t)E * 4);
    unsigned short* w0p = (unsigned short*)carve((size_t)3 * 16384 * 2);
    unsigned short* w1p = (unsigned short*)carve((size_t)3 * 16384 * 2);
    unsigned short* w2p = (unsigned short*)carve((size_t)3 * 8192 * 2);

    const int gridN4 = (N + 3) / 4;
    const int gridE = (E + 255) / 256;
    const int nwaves = (N + 15) / 16;
    const int gridW = (nwaves + 3) / 4;

    // CSR counts + W planes in one dispatch (counts + done zeroed first)
    hipMemsetAsync(counts, 0, (size_t)(ntot + 64) * 4, stream);
    aux_k<<<gridE + 20, 256, 0, stream>>>(dst, E, counts, W0, W1, W2, w0p, w1p, w2p, gridE);
    scan12_k<<<nscan, 256, 0, stream>>>(counts, partials, done, ntot, nscan);
    scan3_k<<<nscan, 256, 0, stream>>>(counts, partials, offs, ntot);
    scatter_k<<<gridE, 256, 0, stream>>>(src, dst, E, counts, csr);

    // ---- layer 0
    normpack_k<<<gridN4, 256, 0, stream>>>(x, bufA, nA, N);
    agg_k<<<N, 64, 0, stream>>>(bufA, nA, offs, csr, bufB, N);
    mgemm_ln_k<<<gridW, 256, 0, stream>>>(bufB, w0p, b0, g1, be1, bufB, nB, nwaves, N);

    // ---- layer 1
    agg_k<<<N, 64, 0, stream>>>(bufB, nB, offs, csr, bufA, N);
    mgemm_ln_k<<<gridW, 256, 0, stream>>>(bufA, w1p, b1, g2, be2, bufA, nA, nwaves, N);

    // ---- layer 2
    agg_k<<<N, 64, 0, stream>>>(bufA, nA, offs, csr, bufB, N);
    mgemm_lsm_k<<<gridW, 256, 0, stream>>>(bufB, w2p, b2, (float*)d_out, nwaves, N);
}

// Round 11
// 341.933 us; speedup vs baseline: 1.0524x; 1.0524x over previous
//
#include <hip/hip_runtime.h>
#include <hip/hip_bf16.h>

#define THR 0.1f
#define COS_EPS 1e-8f
#define LN_EPS 1e-5f

typedef short bfx8 __attribute__((ext_vector_type(8)));
typedef float fx4 __attribute__((ext_vector_type(4)));

__device__ __forceinline__ float wave_sum(float v) {
    #pragma unroll
    for (int o = 1; o < 64; o <<= 1) v += __shfl_xor(v, o);
    return v;
}
__device__ __forceinline__ float gsum16(float v) {
    #pragma unroll
    for (int o = 1; o < 16; o <<= 1) v += __shfl_xor(v, o);
    return v;
}
__device__ __forceinline__ float gmax16(float v) {
    #pragma unroll
    for (int o = 1; o < 16; o <<= 1) v = fmaxf(v, __shfl_xor(v, o));
    return v;
}

__device__ __forceinline__ unsigned short f2bf(float f) {
    unsigned int u = __float_as_uint(f);
    unsigned int r = (u + 0x7FFFu + ((u >> 16) & 1u)) >> 16;
    return (unsigned short)r;
}
__device__ __forceinline__ float bf2f(unsigned short h) {
    return __uint_as_float(((unsigned int)h) << 16);
}

// ---------------- W prep body (value-pinned: no muls -> no contraction risk) ----
template <int CF>
__device__ __forceinline__ void wprep_body(const float* __restrict__ W,
                                           unsigned short* __restrict__ P, int t) {
    const int PLANE = CF * 2048;
    if (t >= 4 * CF * 64) return;
    int lane = t & 63, fr = t >> 6;
    int cf = fr % CF, ks = fr / CF;
    int col = cf * 16 + (lane & 15);
    int k0 = ks * 32 + (lane >> 4) * 8;
    size_t base = (size_t)fr * 512 + (size_t)lane * 8;
    #pragma unroll
    for (int j = 0; j < 8; ++j) {
        float x = W[(size_t)(k0 + j) * (CF * 16) + col];
        unsigned short h = f2bf(x);
        float fh = bf2f(h);
        float r1 = x - fh;
        unsigned short m = f2bf(r1);
        float fm = bf2f(m);
        unsigned short lo = f2bf(r1 - fm);
        P[base + j] = h;
        P[PLANE + base + j] = m;
        P[2 * PLANE + base + j] = lo;
    }
}

// ---------------- fused: edge-degree count + all W plane prep ----------------
__global__ __launch_bounds__(256) void aux_k(const int* __restrict__ dst, int E,
    int* __restrict__ counts, const float* __restrict__ W0, const float* __restrict__ W1,
    const float* __restrict__ W2, unsigned short* __restrict__ P0,
    unsigned short* __restrict__ P1, unsigned short* __restrict__ P2, int gridE) {
    int bx = blockIdx.x;
    if (bx < gridE) {
        int e = bx * 256 + threadIdx.x;
        if (e < E) atomicAdd(&counts[dst[e]], 1);
    } else {
        int r = bx - gridE;
        if (r < 8) wprep_body<8>(W0, P0, r * 256 + threadIdx.x);
        else if (r < 16) wprep_body<8>(W1, P1, (r - 8) * 256 + threadIdx.x);
        else wprep_body<4>(W2, P2, (r - 16) * 256 + threadIdx.x);
    }
}

// fused scan phase 1+2: per-1024-chunk sums; last block scans the <=64 partials
__global__ void scan12_k(const int* __restrict__ counts, int* __restrict__ partials,
                         int* __restrict__ done, int ntot, int nb) {
    int base = blockIdx.x * 1024;
    int t = threadIdx.x;
    int s = 0;
    #pragma unroll
    for (int i = 0; i < 4; ++i) {
        int idx = base + t + i * 256;
        if (idx < ntot) s += counts[idx];
    }
    s = (int)wave_sum((float)s);  // exact: partial sums << 2^24
    __shared__ int ws[4];
    __shared__ int amLast;
    if ((t & 63) == 0) ws[t >> 6] = s;
    __syncthreads();
    if (t == 0) {
        partials[blockIdx.x] = ws[0] + ws[1] + ws[2] + ws[3];
        __threadfence();
        amLast = (atomicAdd(done, 1) == (int)gridDim.x - 1);
    }
    __syncthreads();
    if (amLast && t < 64) {
        __threadfence();
        int v = (t < nb) ? partials[t] : 0;
        int orig = v;
        #pragma unroll
        for (int o = 1; o < 64; o <<= 1) {
            int u = __shfl_up(v, o);
            if (t >= o) v += u;
        }
        if (t < nb) partials[t] = v - orig;
    }
}

__global__ void scan3_k(int* __restrict__ counts, const int* __restrict__ partials,
                        int* __restrict__ offs, int ntot) {
    int base = blockIdx.x * 1024;
    int t = threadIdx.x;
    int lane = t & 63, wid = t >> 6;
    int idx = base + t * 4;
    int c[4];
    #pragma unroll
    for (int k = 0; k < 4; ++k) c[k] = (idx + k < ntot) ? counts[idx + k] : 0;
    int s = c[0] + c[1] + c[2] + c[3];
    int sc = s;
    #pragma unroll
    for (int o = 1; o < 64; o <<= 1) {
        int u = __shfl_up(sc, o);
        if (lane >= o) sc += u;
    }
    __shared__ int wsum[4];
    if (lane == 63) wsum[wid] = sc;
    __syncthreads();
    int add = partials[blockIdx.x];
    for (int w = 0; w < wid; ++w) add += wsum[w];
    int ex = add + sc - s;
    #pragma unroll
    for (int k = 0; k < 4; ++k) {
        if (idx + k < ntot) {
            offs[idx + k] = ex;
            counts[idx + k] = ex;
            ex += c[k];
        }
    }
}

__global__ void scatter_k(const int* __restrict__ src, const int* __restrict__ dst, int E,
                          int* __restrict__ cursor, int* __restrict__ csr_src) {
    int e = blockIdx.x * 256 + threadIdx.x;
    if (e < E) {
        int p = atomicAdd(&cursor[dst[e]], 1);
        csr_src[p] = src[e];
    }
}

// ---------------- normalize x -> hn + norms (FROZEN: byte-exact R5/R8) ----------------
__global__ void normpack_k(const float* __restrict__ h, float* __restrict__ hn,
                           float* __restrict__ norms, int n) {
    int node = (blockIdx.x * blockDim.x + threadIdx.x) >> 6;
    int lane = threadIdx.x & 63;
    if (node >= n) return;
    float2 v = *(const float2*)(h + (size_t)node * 128 + lane * 2);
    float ss = wave_sum(v.x * v.x + v.y * v.y);
    float nrm = sqrtf(ss);
    float inv = 1.0f / fmaxf(nrm, COS_EPS);
    float2 o = {v.x * inv, v.y * inv};
    *(float2*)(hn + (size_t)node * 128 + lane * 2) = o;
    if (lane == 0) norms[node] = nrm;
}

// ---------------- aggregation: R8 depth-2, GUARDED prefetch ----------------
// Guard condition == consumption-keep condition, so every KEPT t is computed
// from identical bits as R8; skipped loads only ever feed discarded t's.
// Slots pre-initialized from own row (no undef reads).
__global__ void agg_k(const float* __restrict__ hn, const float* __restrict__ norms,
                      const int* __restrict__ offs, const int* __restrict__ csr,
                      float* __restrict__ r, int n) {
    int node = (blockIdx.x * blockDim.x + threadIdx.x) >> 6;
    int lane = threadIdx.x & 63;
    if (node >= n) return;
    int g = lane >> 4;
    int q = lane & 15;
    const float* myrow = hn + (size_t)node * 128 + q * 8;
    float4 d0 = *(const float4*)myrow;
    float4 d1 = *(const float4*)(myrow + 4);
    float nd = norms[node];
    float p = d0.x * d0.x + d0.y * d0.y + d0.z * d0.z + d0.w * d0.w
            + d1.x * d1.x + d1.y * d1.y + d1.z * d1.z + d1.w * d1.w;
    p = gsum16(p);
    float4 a0 = {0.f, 0.f, 0.f, 0.f}, a1 = {0.f, 0.f, 0.f, 0.f};
    float denom = 0.f;
    // prefetch slots, initialized (values only ever feed discarded lanes)
    float4 e0a = d0, e0b = d1, e1a = d0, e1b = d1;
    float e0n = nd, e1n = nd;
    int b = offs[node], e = offs[node + 1];
    for (int i0 = b; i0 < e; i0 += 64) {
        int cnt = e - i0;
        if (cnt > 64) cnt = 64;
        int sidx = csr[i0 + (lane < cnt ? lane : 0)];
        {
            int s0 = __shfl(sidx, (g < cnt) ? g : 0);
            if (g < cnt) {
                const float* sp0 = hn + (size_t)s0 * 128 + q * 8;
                e0a = *(const float4*)sp0;
                e0b = *(const float4*)(sp0 + 4);
                e0n = norms[s0];
            }
        }
        {
            int jp1 = 4 + g;
            int s1 = __shfl(sidx, (jp1 < cnt) ? jp1 : 0);
            if (jp1 < cnt) {
                const float* sp1 = hn + (size_t)s1 * 128 + q * 8;
                e1a = *(const float4*)sp1;
                e1b = *(const float4*)(sp1 + 4);
                e1n = norms[s1];
            }
        }
        for (int j = 0; j < cnt; j += 4) {
            float4 c0 = e0a, c1 = e0b;
            float cn = e0n;
            e0a = e1a; e0b = e1b; e0n = e1n;
            int jn = j + 8 + g;
            int s2 = __shfl(sidx, (jn < cnt) ? jn : 0);
            if (jn < cnt) {
                const float* sp2 = hn + (size_t)s2 * 128 + q * 8;
                e1a = *(const float4*)sp2;
                e1b = *(const float4*)(sp2 + 4);
                e1n = norms[s2];
            }
            float t = d0.x * c0.x + d0.y * c0.y + d0.z * c0.z + d0.w * c0.w
                    + d1.x * c1.x + d1.y * c1.y + d1.z * c1.z + d1.w * c1.w;
            t = gsum16(t);
            if (j + g < cnt) {
                float av = (t < THR) ? 1e-6f : t;
                denom += av;
                float w = av * cn;
                a0.x += w * c0.x; a0.y += w * c0.y; a0.z += w * c0.z; a0.w += w * c0.w;
                a1.x += w * c1.x; a1.y += w * c1.y; a1.z += w * c1.z; a1.w += w * c1.w;
            }
        }
    }
    #pragma unroll
    for (int o = 16; o < 64; o <<= 1) {
        a0.x += __shfl_xor(a0.x, o); a0.y += __shfl_xor(a0.y, o);
        a0.z += __shfl_xor(a0.z, o); a0.w += __shfl_xor(a0.w, o);
        a1.x += __shfl_xor(a1.x, o); a1.y += __shfl_xor(a1.y, o);
        a1.z += __shfl_xor(a1.z, o); a1.w += __shfl_xor(a1.w, o);
        denom += __shfl_xor(denom, o);
    }
    // self loop
    float a = (p < THR) ? 1e-6f : p;
    denom += a;
    float w = a * nd;
    a0.x += w * d0.x; a0.y += w * d0.y; a0.z += w * d0.z; a0.w += w * d0.w;
    a1.x += w * d1.x; a1.y += w * d1.y; a1.z += w * d1.z; a1.w += w * d1.w;
    if (g == 0) {
        float inv = 1.0f / denom;
        float4 o0 = {a0.x * inv, a0.y * inv, a0.z * inv, a0.w * inv};
        float4 o1 = {a1.x * inv, a1.y * inv, a1.z * inv, a1.w * inv};
        *(float4*)(r + (size_t)node * 128 + q * 8) = o0;
        *(float4*)(r + (size_t)node * 128 + q * 8 + 4) = o1;
    }
}

// ---------------- MFMA core (FROZEN: byte-exact R5) ----------------
template <int CF>
__device__ __forceinline__ void mfma_core(const float* __restrict__ arow,
                                          const unsigned short* __restrict__ P,
                                          int lane, fx4* acc) {
    const int PLANE = CF * 2048;
    float ast[32];
    #pragma unroll
    for (int ks = 0; ks < 4; ++ks) {
        float4 u0 = *(const float4*)(arow + ks * 32);
        float4 u1 = *(const float4*)(arow + ks * 32 + 4);
        ast[ks * 8 + 0] = u0.x; ast[ks * 8 + 1] = u0.y;
        ast[ks * 8 + 2] = u0.z; ast[ks * 8 + 3] = u0.w;
        ast[ks * 8 + 4] = u1.x; ast[ks * 8 + 5] = u1.y;
        ast[ks * 8 + 6] = u1.z; ast[ks * 8 + 7] = u1.w;
    }
    #pragma unroll
    for (int ks = 0; ks < 4; ++ks) {
        bfx8 ah, am, al;
        #pragma unroll
        for (int j = 0; j < 8; ++j) {
            float x = ast[ks * 8 + j];
            unsigned short h = f2bf(x);
            float fh = bf2f(h);
            float r1 = x - fh;
            unsigned short m = f2bf(r1);
            float fm = bf2f(m);
            unsigned short lo = f2bf(r1 - fm);
            ah[j] = (short)h; am[j] = (short)m; al[j] = (short)lo;
        }
        #pragma unroll
        for (int cb = 0; cb < CF; cb += 4) {
            bfx8 bh[4], bm[4], bl[4];
            #pragma unroll
            for (int q = 0; q < 4; ++q) {
                size_t base = ((size_t)(ks * CF + cb + q) * 64 + lane) * 8;
                bh[q] = *(const bfx8*)(P + base);
                bm[q] = *(const bfx8*)(P + PLANE + base);
                bl[q] = *(const bfx8*)(P + 2 * PLANE + base);
            }
            #pragma unroll
            for (int q = 0; q < 4; ++q)
                acc[cb + q] = __builtin_amdgcn_mfma_f32_16x16x32_bf16(ah, bh[q], acc[cb + q], 0, 0, 0);
            #pragma unroll
            for (int q = 0; q < 4; ++q)
                acc[cb + q] = __builtin_amdgcn_mfma_f32_16x16x32_bf16(ah, bm[q], acc[cb + q], 0, 0, 0);
            #pragma unroll
            for (int q = 0; q < 4; ++q)
                acc[cb + q] = __builtin_amdgcn_mfma_f32_16x16x32_bf16(am, bh[q], acc[cb + q], 0, 0, 0);
            #pragma unroll
            for (int q = 0; q < 4; ++q)
                acc[cb + q] = __builtin_amdgcn_mfma_f32_16x16x32_bf16(ah, bl[q], acc[cb + q], 0, 0, 0);
            #pragma unroll
            for (int q = 0; q < 4; ++q)
                acc[cb + q] = __builtin_amdgcn_mfma_f32_16x16x32_bf16(am, bm[q], acc[cb + q], 0, 0, 0);
            #pragma unroll
            for (int q = 0; q < 4; ++q)
                acc[cb + q] = __builtin_amdgcn_mfma_f32_16x16x32_bf16(al, bh[q], acc[cb + q], 0, 0, 0);
        }
    }
}

// ---------------- MFMA GEMM + bias + LN + ReLU + renormalize (FROZEN: R5) ----------------
__global__ __launch_bounds__(256) void mgemm_ln_k(const float* __restrict__ A,
    const unsigned short* __restrict__ P, const float* __restrict__ bias,
    const float* __restrict__ g, const float* __restrict__ be,
    float* __restrict__ hn, float* __restrict__ norms, int nw, int M) {
    const int CF = 8;
    int wid = blockIdx.x * 4 + (threadIdx.x >> 6);
    if (wid >= nw) return;
    int lane = threadIdx.x & 63;
    int rsel = lane & 15, kg = lane >> 4;
    int arowi = wid * 16 + rsel;
    if (arowi >= M) arowi = M - 1;
    const float* arow = A + (size_t)arowi * 128 + kg * 8;
    fx4 acc[CF];
    #pragma unroll
    for (int c = 0; c < CF; ++c) acc[c] = (fx4){0.f, 0.f, 0.f, 0.f};
    mfma_core<CF>(arow, P, lane, acc);
    float bi[CF], gm[CF], bb[CF];
    #pragma unroll
    for (int c = 0; c < CF; ++c) {
        int col = c * 16 + rsel;
        bi[c] = bias[col]; gm[c] = g[col]; bb[c] = be[col];
    }
    #pragma unroll
    for (int r = 0; r < 4; ++r) {
        int row = wid * 16 + kg * 4 + r;
        float o[CF], s = 0.f;
        #pragma unroll
        for (int c = 0; c < CF; ++c) { o[c] = acc[c][r] + bi[c]; s += o[c]; }
        float mean = gsum16(s) * (1.f / 128.f);
        float vv = 0.f;
        #pragma unroll
        for (int c = 0; c < CF; ++c) { o[c] -= mean; vv += o[c] * o[c]; }
        float var = gsum16(vv) * (1.f / 128.f);
        float rs = rsqrtf(var + LN_EPS);
        float ss = 0.f;
        #pragma unroll
        for (int c = 0; c < CF; ++c) {
            o[c] = fmaxf(o[c] * rs * gm[c] + bb[c], 0.f);
            ss += o[c] * o[c];
        }
        float nrm = sqrtf(gsum16(ss));
        float inv = 1.f / fmaxf(nrm, COS_EPS);
        if (row < M) {
            #pragma unroll
            for (int c = 0; c < CF; ++c) hn[(size_t)row * 128 + c * 16 + rsel] = o[c] * inv;
            if (rsel == 0) norms[row] = nrm;
        }
    }
}

// ---------------- MFMA GEMM + bias + log_softmax (FROZEN: R5) ----------------
__global__ __launch_bounds__(256) void mgemm_lsm_k(const float* __restrict__ A,
    const unsigned short* __restrict__ P, const float* __restrict__ bias,
    float* __restrict__ out, int nw, int M) {
    const int CF = 4;
    int wid = blockIdx.x * 4 + (threadIdx.x >> 6);
    if (wid >= nw) return;
    int lane = threadIdx.x & 63;
    int rsel = lane & 15, kg = lane >> 4;
    int arowi = wid * 16 + rsel;
    if (arowi >= M) arowi = M - 1;
    const float* arow = A + (size_t)arowi * 128 + kg * 8;
    fx4 acc[CF];
    #pragma unroll
    for (int c = 0; c < CF; ++c) acc[c] = (fx4){0.f, 0.f, 0.f, 0.f};
    mfma_core<CF>(arow, P, lane, acc);
    float bi[CF];
    #pragma unroll
    for (int c = 0; c < CF; ++c) bi[c] = bias[c * 16 + rsel];
    #pragma unroll
    for (int r = 0; r < 4; ++r) {
        int row = wid * 16 + kg * 4 + r;
        float v[CF], mx = -1e30f;
        #pragma unroll
        for (int c = 0; c < CF; ++c) { v[c] = acc[c][r] + bi[c]; mx = fmaxf(mx, v[c]); }
        float m = gmax16(mx);
        float es = 0.f;
        #pragma unroll
        for (int c = 0; c < CF; ++c) es += __expf(v[c] - m);
        float s = gsum16(es);
        float ls = logf(s);
        if (row < M) {
            #pragma unroll
            for (int c = 0; c < CF; ++c) out[(size_t)row * 64 + c * 16 + rsel] = v[c] - m - ls;
        }
    }
}

extern "C" void kernel_launch(void* const* d_in, const int* in_sizes, int n_in,
                              void* d_out, int out_size, void* d_ws, size_t ws_size,
                              hipStream_t stream) {
    const float* x  = (const float*)d_in[0];
    const int* ei   = (const int*)d_in[1];
    const float* W0 = (const float*)d_in[2];
    const float* b0 = (const float*)d_in[3];
    const float* W1 = (const float*)d_in[4];
    const float* b1 = (const float*)d_in[5];
    const float* W2 = (const float*)d_in[6];
    const float* b2 = (const float*)d_in[7];
    const float* g1 = (const float*)d_in[8];
    const float* be1 = (const float*)d_in[9];
    const float* g2 = (const float*)d_in[10];
    const float* be2 = (const float*)d_in[11];

    const int N = in_sizes[0] / 128;
    const int E = in_sizes[1] / 2;
    const int* src = ei;
    const int* dst = ei + E;
    const int ntot = N + 1;
    const int nscan = (ntot + 1023) / 1024;

    size_t off = 0;
    auto carve = [&](size_t bytes) {
        void* p = (char*)d_ws + off;
        off += (bytes + 255) & ~(size_t)255;
        return p;
    };
    float* bufA   = (float*)carve((size_t)N * 128 * 4);
    float* bufB   = (float*)carve((size_t)N * 128 * 4);
    float* nA     = (float*)carve((size_t)N * 4);
    float* nB     = (float*)carve((size_t)N * 4);
    int* counts   = (int*)carve((size_t)(ntot + 64) * 4);  // +done counter
    int* done     = counts + ntot;
    int* offs     = (int*)carve((size_t)ntot * 4);
    int* partials = (int*)carve((size_t)256 * 4);
    int* csr      = (int*)carve((size_t)E * 4);
    unsigned short* w0p = (unsigned short*)carve((size_t)3 * 16384 * 2);
    unsigned short* w1p = (unsigned short*)carve((size_t)3 * 16384 * 2);
    unsigned short* w2p = (unsigned short*)carve((size_t)3 * 8192 * 2);

    const int gridN4 = (N + 3) / 4;
    const int gridE = (E + 255) / 256;
    const int nwaves = (N + 15) / 16;
    const int gridW = (nwaves + 3) / 4;

    // CSR counts + W planes in one dispatch (counts + done zeroed first)
    hipMemsetAsync(counts, 0, (size_t)(ntot + 64) * 4, stream);
    aux_k<<<gridE + 20, 256, 0, stream>>>(dst, E, counts, W0, W1, W2, w0p, w1p, w2p, gridE);
    scan12_k<<<nscan, 256, 0, stream>>>(counts, partials, done, ntot, nscan);
    scan3_k<<<nscan, 256, 0, stream>>>(counts, partials, offs, ntot);
    scatter_k<<<gridE, 256, 0, stream>>>(src, dst, E, counts, csr);

    // ---- layer 0
    normpack_k<<<gridN4, 256, 0, stream>>>(x, bufA, nA, N);
    agg_k<<<gridN4, 256, 0, stream>>>(bufA, nA, offs, csr, bufB, N);
    mgemm_ln_k<<<gridW, 256, 0, stream>>>(bufB, w0p, b0, g1, be1, bufB, nB, nwaves, N);

    // ---- layer 1
    agg_k<<<gridN4, 256, 0, stream>>>(bufB, nB, offs, csr, bufA, N);
    mgemm_ln_k<<<gridW, 256, 0, stream>>>(bufA, w1p, b1, g2, be2, bufA, nA, nwaves, N);

    // ---- layer 2
    agg_k<<<gridN4, 256, 0, stream>>>(bufA, nA, offs, csr, bufB, N);
    mgemm_lsm_k<<<gridW, 256, 0, stream>>>(bufB, w2p, b2, (float*)d_out, nwaves, N);
}